// Round 6
// baseline (1363.673 us; speedup 1.0000x reference)
//
#include <hip/hip_runtime.h>
#include <hip/hip_bf16.h>

// BitNet-style ternary MLP: out = relu(x @ Wfc_q^T * s_fc)^2 @ Wproj_q^T * s_proj
// B=8 S=4096 D=2048 H=5120 -> M=32768.
// GEMMs: 256x256 tile, BK=64, 8 waves, 4 phases/K-tile (m201-style schedule,
// round-5 staging order + vmcnt(4) gate), now with v_mfma_f32_32x32x16_bf16
// (32x32 shape runs at 2495 TF ubench vs ~2100 for 16x16; half the MFMA
// instruction count). T2 swizzle via pre-swizzled global src; T5 setprio;
// T1 bijective XCD swizzle.

typedef __attribute__((ext_vector_type(8))) short short8;
typedef __attribute__((ext_vector_type(16))) float f32x16;

#define BM 256
#define BN 256
#define BK 64

__device__ __forceinline__ unsigned short f2bf(float f) {
  unsigned int u = __float_as_uint(f);
  u += 0x7FFFu + ((u >> 16) & 1u);  // RNE
  return (unsigned short)(u >> 16);
}

__device__ __forceinline__ void gload_lds16(const void* gsrc, void* ldst) {
  __builtin_amdgcn_global_load_lds(
      (const __attribute__((address_space(1))) unsigned int*)gsrc,
      (__attribute__((address_space(3))) unsigned int*)ldst, 16, 0, 0);
}

// ---------- pass 1: |w| sum partials (deterministic, fp64 accumulate) ----------
__global__ void k_reduce_abs(const float4* __restrict__ w, int n4,
                             double* __restrict__ partial) {
  __shared__ double sm[256];
  double s = 0.0;
  const int stride = gridDim.x * blockDim.x;
  for (int i = blockIdx.x * blockDim.x + threadIdx.x; i < n4; i += stride) {
    float4 v = w[i];
    s += (double)fabsf(v.x);
    s += (double)fabsf(v.y);
    s += (double)fabsf(v.z);
    s += (double)fabsf(v.w);
  }
  sm[threadIdx.x] = s;
  __syncthreads();
  for (int off = 128; off > 0; off >>= 1) {
    if (threadIdx.x < off) sm[threadIdx.x] += sm[threadIdx.x + off];
    __syncthreads();
  }
  if (threadIdx.x == 0) partial[blockIdx.x] = sm[0];
}

// ---------- pass 2: finalize abs_mean / thr for both weights ----------
__global__ void k_finalize(const double* __restrict__ partial,
                           float* __restrict__ scales, double inv_n) {
  __shared__ double sm[256];
  const int t = threadIdx.x;
  for (int seg = 0; seg < 2; ++seg) {
    const double* p = partial + seg * 1024;
    double s = p[t * 4] + p[t * 4 + 1] + p[t * 4 + 2] + p[t * 4 + 3];
    sm[t] = s;
    __syncthreads();
    for (int off = 128; off > 0; off >>= 1) {
      if (t < off) sm[t] += sm[t + off];
      __syncthreads();
    }
    if (t == 0) {
      float am = (float)(sm[0] * inv_n);
      am = fmaxf(am, 1e-5f);
      scales[seg * 2] = am;             // abs_mean
      scales[seg * 2 + 1] = 0.7f * am;  // threshold
    }
    __syncthreads();
  }
}

// ---------- ternarize: fp32 w -> bf16 q in {-1,0,+1} ----------
__global__ void k_ternarize(const float4* __restrict__ w, ushort4* __restrict__ q,
                            const float* __restrict__ scales, int sidx, int n4) {
  const float thr = scales[sidx * 2 + 1];
  const int stride = gridDim.x * blockDim.x;
  for (int i = blockIdx.x * blockDim.x + threadIdx.x; i < n4; i += stride) {
    float4 v = w[i];
    ushort4 o;
    o.x = v.x > thr ? 0x3F80u : (v.x < -thr ? 0xBF80u : 0u);
    o.y = v.y > thr ? 0x3F80u : (v.y < -thr ? 0xBF80u : 0u);
    o.z = v.z > thr ? 0x3F80u : (v.z < -thr ? 0xBF80u : 0u);
    o.w = v.w > thr ? 0x3F80u : (v.w < -thr ? 0xBF80u : 0u);
    q[i] = o;
  }
}

// ---------- x: fp32 -> bf16 ----------
__global__ void k_f32_to_bf16(const float4* __restrict__ x, ushort4* __restrict__ o,
                              int n4) {
  const int stride = gridDim.x * blockDim.x;
  for (int i = blockIdx.x * blockDim.x + threadIdx.x; i < n4; i += stride) {
    float4 v = x[i];
    ushort4 r;
    r.x = f2bf(v.x);
    r.y = f2bf(v.y);
    r.z = f2bf(v.z);
    r.w = f2bf(v.w);
    o[i] = r;
  }
}

// ================= 256x256 8-wave pipelined GEMM (32x32x16 MFMA) =============
// C = A * B^T. A[M][K], B[N][K] bf16; fp32 acc.
// LDS per buffer: A[256][64] @ +0, B[256][64] @ +16384 (shorts); dbuf = 128 KiB.
// Swizzle: LDS linear; global src col pre-permuted so that
// LDS[row][c8] = G[row][c8 ^ (row&7)] (8-elem chunks); frag reads XOR the same.
// Wave output 128x64 = 4 x 2 tiles of 32x32. Phases (quadrants):
//   P1 (mt 0-1, nt0): reads A0(8)+B0(4);  P2 (mt 2-3, nt0): reads A1(8);
//   P3 (mt 2-3, nt1): reads B1(4);        P4 (mt 0-1, nt1): no reads.
// Staging: P1(T): AQ0+BQ1 (tile T+1); P2(T): BQ0 (T+2); P3(T): AQ1 (T+2).
// Gate: vmcnt(4) at P4-end.

#define ST1(Gst, base, r0, k0)                          \
  gload_lds16(Gst + (size_t)(r0) * K + (k0),            \
              (void*)(lptr + (base) + (r0) * 64))

#define ST_AQ0(pp, k0) do { ST1(Ast, (pp)*32768, w8, k0);        ST1(Ast, (pp)*32768, 128 + w8, k0); } while (0)
#define ST_AQ1(pp, k0) do { ST1(Ast, (pp)*32768, 64 + w8, k0);   ST1(Ast, (pp)*32768, 192 + w8, k0); } while (0)
#define ST_BQ0(pp, k0) do { ST1(Bst, (pp)*32768 + 16384, rb, k0);      ST1(Bst, (pp)*32768 + 16384, 128 + rb, k0); } while (0)
#define ST_BQ1(pp, k0) do { ST1(Bst, (pp)*32768 + 16384, 32 + rb, k0); ST1(Bst, (pp)*32768 + 16384, 160 + rb, k0); } while (0)

// A-half (2 row-tiles of 32) fragments: 8 x ds_read_b128
#define LDA(dst, p_, qr)                                                       \
  do {                                                                         \
    const unsigned short* ab =                                                 \
        lptr + (p_) * 32768 + (wr * 128 + (qr) * 64 + frow) * 64;              \
    _Pragma("unroll") for (int mt2 = 0; mt2 < 2; ++mt2)                        \
    _Pragma("unroll") for (int ks = 0; ks < 4; ++ks)                           \
      dst[mt2][ks] = *(const short8*)(ab + mt2 * 2048 + cswk[ks]);             \
  } while (0)

// B-tile (1 col-tile of 32) fragments: 4 x ds_read_b128
#define LDB(p_, qc)                                                            \
  do {                                                                         \
    const unsigned short* bb =                                                 \
        lptr + (p_) * 32768 + 16384 + (wc * 64 + (qc) * 32 + frow) * 64;       \
    _Pragma("unroll") for (int ks = 0; ks < 4; ++ks)                           \
      bq[ks] = *(const short8*)(bb + cswk[ks]);                                \
  } while (0)

#define MFMA_PHASE(afv, qr, qc)                                                \
  do {                                                                         \
    __builtin_amdgcn_s_setprio(1);                                             \
    _Pragma("unroll") for (int ks = 0; ks < 4; ++ks)                           \
    _Pragma("unroll") for (int mt2 = 0; mt2 < 2; ++mt2)                        \
      acc[(qr) * 2 + mt2][(qc)] = __builtin_amdgcn_mfma_f32_32x32x16_bf16(     \
          afv[mt2][ks], bq[ks], acc[(qr) * 2 + mt2][(qc)], 0, 0, 0);           \
    __builtin_amdgcn_s_setprio(0);                                             \
  } while (0)

#define BAR()                           \
  do {                                  \
    asm volatile("" ::: "memory");      \
    __builtin_amdgcn_s_barrier();       \
    asm volatile("" ::: "memory");      \
  } while (0)

#define WAIT_LGKM0() asm volatile("s_waitcnt lgkmcnt(0)" ::: "memory")

template <int EPI>
__global__ __launch_bounds__(512, 2) void k_gemm_bt(
    const unsigned short* __restrict__ A, const unsigned short* __restrict__ B,
    void* __restrict__ Cout, int M, int N, int K,
    const float* __restrict__ scales, int sidx, int nbx) {
  __shared__ __align__(16) unsigned short lds[2 * 2 * 256 * 64];  // 128 KiB
  unsigned short* lptr = lds;

  const int tid = threadIdx.x;
  const int lane = tid & 63;
  const int w = tid >> 6;   // wave 0..7
  const int wr = w >> 2;    // 0..1 -> 128 rows
  const int wc = w & 3;     // 0..3 -> 64 cols

  // T1: bijective XCD swizzle (gridDim.x % 8 == 0)
  const int nwg = gridDim.x;
  const int cpx = nwg >> 3;
  const int bid = blockIdx.x;
  const int swz = (bid & 7) * cpx + (bid >> 3);
  const int bm = swz / nbx;
  const int bn = swz % nbx;
  const int rowA0 = bm * BM;
  const int rowB0 = bn * BN;

  // staging lane geometry: row within 8-row chunk + pre-swizzled source col
  const int srow = lane >> 3;
  const int scol = ((lane & 7) ^ srow) << 3;  // bf16 elems
  const unsigned short* Ast = A + (size_t)(rowA0 + srow) * K + scol;
  const unsigned short* Bst = B + (size_t)(rowB0 + srow) * K + scol;

  // frag-read lane geometry (32x32x16: lane = row + 32*kgrp, 8 elems at kgrp*8)
  const int frow = lane & 31;              // row within 32-row tile
  const int kb8 = (lane >> 5) << 3;        // k-group base (elems)
  const int rx = (lane & 7) << 3;          // swizzle XOR (elems)
  int cswk[4];
#pragma unroll
  for (int ks = 0; ks < 4; ++ks) cswk[ks] = (ks * 16 + kb8) ^ rx;

  const int w8 = w << 3;
  const int rb = ((w >> 2) << 6) + ((w & 3) << 3);

  f32x16 acc[8][2];
#pragma unroll
  for (int i = 0; i < 8; ++i)
#pragma unroll
    for (int j = 0; j < 2; ++j)
#pragma unroll
      for (int q = 0; q < 16; ++q) acc[i][j][q] = 0.f;

  short8 af0[2][4], af1[2][4], bq[4];

  const int nk = K / BK;

  // prologue (FIFO): tile0 {Bq0,Aq1,Aq0,Bq1}, tile1 {Bq0,Aq1}
  ST_BQ0(0, 0);
  ST_AQ1(0, 0);
  ST_AQ0(0, 0);
  ST_BQ1(0, 0);
  if (nk > 1) {
    ST_BQ0(1, BK);
    ST_AQ1(1, BK);
    asm volatile("s_waitcnt vmcnt(4)" ::: "memory");  // tile0 fully staged
  } else {
    asm volatile("s_waitcnt vmcnt(0)" ::: "memory");
  }
  BAR();

  int p = 0;
  for (int T = 0; T < nk; ++T, p ^= 1) {
    const int pn = p ^ 1;
    const int k1 = (T + 1) * BK;
    const int k2 = (T + 2) * BK;
    const bool more = (T + 2) < nk;

    // ---- P1 (mt0-1, nt0): read A0,B0 pre-barrier; stage AQ0+BQ1 (T+1) ----
    LDA(af0, p, 0);
    LDB(p, 0);
    if (T + 1 < nk) {
      ST_AQ0(pn, k1);
      ST_BQ1(pn, k1);
    }
    asm volatile("s_waitcnt lgkmcnt(8)" ::: "memory");  // partial drain (12 issued)
    BAR();
    WAIT_LGKM0();
    MFMA_PHASE(af0, 0, 0);
    BAR();

    // ---- P2 (mt2-3, nt0): read A1; reuse bq; stage BQ0 (T+2, buf p) ----
    LDA(af1, p, 1);
    if (more) ST_BQ0(p, k2);
    BAR();
    WAIT_LGKM0();
    MFMA_PHASE(af1, 1, 0);
    BAR();

    // ---- P3 (mt2-3, nt1): read B1; reuse af1; stage AQ1 (T+2, buf p) ----
    LDB(p, 1);
    if (more) ST_AQ1(p, k2);
    BAR();
    WAIT_LGKM0();
    MFMA_PHASE(af1, 1, 1);
    BAR();

    // ---- P4 (mt0-1, nt1): no reads (af0 held, bq reused); no staging ----
    BAR();
    MFMA_PHASE(af0, 0, 1);
    // tile-boundary gate: force tile T+1 complete; keep T+2's 4 loads in flight
    if (T + 1 < nk) {
      if (more) {
        asm volatile("s_waitcnt vmcnt(4)" ::: "memory");
      } else {
        asm volatile("s_waitcnt vmcnt(0)" ::: "memory");
      }
    }
    BAR();
  }

  // epilogue: 32x32 C/D layout: col = lane&31, row = (reg&3)+8*(reg>>2)+4*(lane>>5)
  const float s = scales[sidx * 2];
  const int crow0 = rowA0 + wr * 128 + ((lane >> 5) << 2);
  const int ccol0 = rowB0 + wc * 64 + (lane & 31);
  if (EPI == 0) {
    const float s2 = s * s;
    unsigned short* C = (unsigned short*)Cout;
#pragma unroll
    for (int mt = 0; mt < 4; ++mt)
#pragma unroll
      for (int nt = 0; nt < 2; ++nt)
#pragma unroll
        for (int reg = 0; reg < 16; ++reg) {
          float v = acc[mt * 2 / 2 * 2 + (mt & 1)][nt][reg];  // acc[mt][nt]
          v = acc[mt][nt][reg];
          v = fmaxf(v, 0.0f);
          v = v * v * s2;
          const int row = crow0 + mt * 32 + (reg & 3) + ((reg >> 2) << 3);
          C[(size_t)row * N + (ccol0 + nt * 32)] = f2bf(v);
        }
  } else {
    float* C = (float*)Cout;
#pragma unroll
    for (int mt = 0; mt < 4; ++mt)
#pragma unroll
      for (int nt = 0; nt < 2; ++nt)
#pragma unroll
        for (int reg = 0; reg < 16; ++reg) {
          const int row = crow0 + mt * 32 + (reg & 3) + ((reg >> 2) << 3);
          C[(size_t)row * N + (ccol0 + nt * 32)] = acc[mt][nt][reg] * s;
        }
  }
}

extern "C" void kernel_launch(void* const* d_in, const int* in_sizes, int n_in,
                              void* d_out, int out_size, void* d_ws, size_t ws_size,
                              hipStream_t stream) {
  const int Mdim = 32768;  // B*S
  const int Ddim = 2048;
  const int Hdim = 5120;
  const int NW = Hdim * Ddim;  // elements per weight

  const float* x = (const float*)d_in[0];
  const float* w_fc = (const float*)d_in[1];
  const float* w_proj = (const float*)d_in[2];
  float* out = (float*)d_out;

  char* ws = (char*)d_ws;
  double* partial = (double*)ws;                          // 16 KB
  float* scales = (float*)(ws + 16384);                   // 4 floats
  unsigned short* wq_fc = (unsigned short*)(ws + 32768);  // 20 MB
  unsigned short* wq_proj = wq_fc + (size_t)NW;           // 20 MB
  unsigned short* xbf = wq_proj + (size_t)NW;             // 128 MB
  unsigned short* hbf = xbf + (size_t)Mdim * Ddim;        // 320 MB

  // 1) abs-mean reductions (deterministic, fp64)
  k_reduce_abs<<<1024, 256, 0, stream>>>((const float4*)w_fc, NW / 4, partial);
  k_reduce_abs<<<1024, 256, 0, stream>>>((const float4*)w_proj, NW / 4,
                                         partial + 1024);
  k_finalize<<<1, 256, 0, stream>>>(partial, scales, 1.0 / (double)NW);

  // 2) ternarize weights -> bf16 q
  k_ternarize<<<2048, 256, 0, stream>>>((const float4*)w_fc, (ushort4*)wq_fc,
                                        scales, 0, NW / 4);
  k_ternarize<<<2048, 256, 0, stream>>>((const float4*)w_proj, (ushort4*)wq_proj,
                                        scales, 1, NW / 4);

  // 3) x -> bf16
  k_f32_to_bf16<<<2048, 256, 0, stream>>>((const float4*)x, (ushort4*)xbf,
                                          (Mdim * Ddim) / 4);

  // 4) h = relu(x @ Wfc^T * s)^2  [M x H] bf16
  k_gemm_bt<0><<<dim3((Hdim / BN) * (Mdim / BM)), 512, 0, stream>>>(
      xbf, wq_fc, hbf, Mdim, Hdim, Ddim, scales, 0, Hdim / BN);

  // 5) out = h @ Wproj^T * s  [M x D] fp32
  k_gemm_bt<1><<<dim3((Ddim / BN) * (Mdim / BM)), 512, 0, stream>>>(
      hbf, wq_proj, out, Mdim, Ddim, Hdim, scales, 1, Ddim / BN);
}

// Round 7
// 1340.781 us; speedup vs baseline: 1.0171x; 1.0171x over previous
//
#include <hip/hip_runtime.h>
#include <hip/hip_bf16.h>

// BitNet-style ternary MLP: out = relu(x @ Wfc_q^T * s_fc)^2 @ Wproj_q^T * s_proj
// B=8 S=4096 D=2048 H=5120 -> M=32768.
// GEMMs: 256x256 tile, BK=32, 8 waves, 16x16x32 MFMA, THREE LDS buffers
// (96 KiB) with ONE barrier per K-tile: stage T+2 -> freed buffer, read tile T,
// 32 MFMA, counted vmcnt(4) gate (never drains), s_barrier. Compiler-scheduled
// lgkmcnt (no sched_barrier pinning). T2 swizzle (4-chunk domain) via
// pre-swizzled global src; T5 setprio; T1 bijective XCD swizzle.

typedef __attribute__((ext_vector_type(8))) short short8;
typedef __attribute__((ext_vector_type(4))) float f32x4;

#define BM 256
#define BN 256
#define BK 32
#define BUFE 16384  // elems (shorts) per buffer: A[256][32] + B[256][32]

__device__ __forceinline__ unsigned short f2bf(float f) {
  unsigned int u = __float_as_uint(f);
  u += 0x7FFFu + ((u >> 16) & 1u);  // RNE
  return (unsigned short)(u >> 16);
}

__device__ __forceinline__ void gload_lds16(const void* gsrc, void* ldst) {
  __builtin_amdgcn_global_load_lds(
      (const __attribute__((address_space(1))) unsigned int*)gsrc,
      (__attribute__((address_space(3))) unsigned int*)ldst, 16, 0, 0);
}

// ---------- pass 1: |w| sum partials (deterministic, fp64 accumulate) ----------
__global__ void k_reduce_abs(const float4* __restrict__ w, int n4,
                             double* __restrict__ partial) {
  __shared__ double sm[256];
  double s = 0.0;
  const int stride = gridDim.x * blockDim.x;
  for (int i = blockIdx.x * blockDim.x + threadIdx.x; i < n4; i += stride) {
    float4 v = w[i];
    s += (double)fabsf(v.x);
    s += (double)fabsf(v.y);
    s += (double)fabsf(v.z);
    s += (double)fabsf(v.w);
  }
  sm[threadIdx.x] = s;
  __syncthreads();
  for (int off = 128; off > 0; off >>= 1) {
    if (threadIdx.x < off) sm[threadIdx.x] += sm[threadIdx.x + off];
    __syncthreads();
  }
  if (threadIdx.x == 0) partial[blockIdx.x] = sm[0];
}

// ---------- pass 2: finalize abs_mean / thr for both weights ----------
__global__ void k_finalize(const double* __restrict__ partial,
                           float* __restrict__ scales, double inv_n) {
  __shared__ double sm[256];
  const int t = threadIdx.x;
  for (int seg = 0; seg < 2; ++seg) {
    const double* p = partial + seg * 1024;
    double s = p[t * 4] + p[t * 4 + 1] + p[t * 4 + 2] + p[t * 4 + 3];
    sm[t] = s;
    __syncthreads();
    for (int off = 128; off > 0; off >>= 1) {
      if (t < off) sm[t] += sm[t + off];
      __syncthreads();
    }
    if (t == 0) {
      float am = (float)(sm[0] * inv_n);
      am = fmaxf(am, 1e-5f);
      scales[seg * 2] = am;             // abs_mean
      scales[seg * 2 + 1] = 0.7f * am;  // threshold
    }
    __syncthreads();
  }
}

// ---------- ternarize: fp32 w -> bf16 q in {-1,0,+1} ----------
__global__ void k_ternarize(const float4* __restrict__ w, ushort4* __restrict__ q,
                            const float* __restrict__ scales, int sidx, int n4) {
  const float thr = scales[sidx * 2 + 1];
  const int stride = gridDim.x * blockDim.x;
  for (int i = blockIdx.x * blockDim.x + threadIdx.x; i < n4; i += stride) {
    float4 v = w[i];
    ushort4 o;
    o.x = v.x > thr ? 0x3F80u : (v.x < -thr ? 0xBF80u : 0u);
    o.y = v.y > thr ? 0x3F80u : (v.y < -thr ? 0xBF80u : 0u);
    o.z = v.z > thr ? 0x3F80u : (v.z < -thr ? 0xBF80u : 0u);
    o.w = v.w > thr ? 0x3F80u : (v.w < -thr ? 0xBF80u : 0u);
    q[i] = o;
  }
}

// ---------- x: fp32 -> bf16 ----------
__global__ void k_f32_to_bf16(const float4* __restrict__ x, ushort4* __restrict__ o,
                              int n4) {
  const int stride = gridDim.x * blockDim.x;
  for (int i = blockIdx.x * blockDim.x + threadIdx.x; i < n4; i += stride) {
    float4 v = x[i];
    ushort4 r;
    r.x = f2bf(v.x);
    r.y = f2bf(v.y);
    r.z = f2bf(v.z);
    r.w = f2bf(v.w);
    o[i] = r;
  }
}

// ============ 256x256 8-wave, BK=32, 3-buffer, 1-barrier/tile GEMM ============
// C = A * B^T. A[M][K], B[N][K] bf16; fp32 acc.
// Buffer i at elem offset i*BUFE: A[256][32] @ +0, B[256][32] @ +8192.
// Swizzle (4 chunks of 16B per 64B row): LDS[row][c] = G[row][c ^ ((row>>1)&3)];
// frag reads use chunk = kgrp ^ ((fr>>1)&3)  (8 bank-quads, 2-way free aliasing).
// Per tile: stage T+2 (4 gloads) -> buffer freed by T-1; 12 ds_read_b128;
// 32 MFMA (2 setprio clusters); vmcnt(4); s_barrier. Rotation cur<-nxt<-stg.

// one global_load_lds: 1 KB = 16 rows x 64 B; wave-uniform r0
#define ST1(Gst, bufo, r0, k0)                        \
  gload_lds16(Gst + (size_t)(r0) * K + (k0),          \
              (void*)(lptr + (bufo) + (r0) * 32))

#define ST_A(bufo, k0) do { ST1(Ast, (bufo), w16, k0); ST1(Ast, (bufo), 128 + w16, k0); } while (0)
#define ST_B(bufo, k0) do { ST1(Bst, (bufo) + 8192, w16, k0); ST1(Bst, (bufo) + 8192, 128 + w16, k0); } while (0)

#define BAR()                           \
  do {                                  \
    asm volatile("" ::: "memory");      \
    __builtin_amdgcn_s_barrier();       \
    asm volatile("" ::: "memory");      \
  } while (0)

template <int EPI>
__global__ __launch_bounds__(512, 2) void k_gemm_bt(
    const unsigned short* __restrict__ A, const unsigned short* __restrict__ B,
    void* __restrict__ Cout, int M, int N, int K,
    const float* __restrict__ scales, int sidx, int nbx) {
  __shared__ __align__(16) unsigned short lds[3 * BUFE];  // 96 KiB
  unsigned short* lptr = lds;

  const int tid = threadIdx.x;
  const int lane = tid & 63;
  const int w = tid >> 6;   // wave 0..7
  const int wr = w >> 2;    // 0..1 -> 128 rows
  const int wc = w & 3;     // 0..3 -> 64 cols

  // T1: bijective XCD swizzle (gridDim.x % 8 == 0)
  const int nwg = gridDim.x;
  const int cpx = nwg >> 3;
  const int bid = blockIdx.x;
  const int swz = (bid & 7) * cpx + (bid >> 3);
  const int bm = swz / nbx;
  const int bn = swz % nbx;
  const int rowA0 = bm * BM;
  const int rowB0 = bn * BN;

  // staging lane geometry: 16 rows/instr; source col pre-swizzled (4-chunk dom)
  const int srow = lane >> 2;                              // 0..15
  const int scol = ((lane & 3) ^ ((lane >> 3) & 3)) << 3;  // elems
  const unsigned short* Ast = A + (size_t)(rowA0 + srow) * K + scol;
  const unsigned short* Bst = B + (size_t)(rowB0 + srow) * K + scol;

  // frag-read lane geometry: fr = row within 16-tile, kgrp = k-chunk
  const int fr = lane & 15;
  const int kgrp = lane >> 4;
  const int csw = ((kgrp ^ ((fr >> 1) & 3)) << 3);         // elems
  const int aoff = (wr * 128 + fr) * 32 + csw;
  const int boff = 8192 + (wc * 64 + fr) * 32 + csw;

  const int w16 = w << 4;

  f32x4 acc[8][4];
#pragma unroll
  for (int i = 0; i < 8; ++i)
#pragma unroll
    for (int j = 0; j < 4; ++j) acc[i][j] = (f32x4){0.f, 0.f, 0.f, 0.f};

  const int nk = K / BK;

  // prologue: stage T0 -> buf0, T1 -> buf1; wait T0; barrier
  ST_A(0, 0);
  ST_B(0, 0);
  if (nk > 1) {
    ST_A(BUFE, BK);
    ST_B(BUFE, BK);
    asm volatile("s_waitcnt vmcnt(4)" ::: "memory");
  } else {
    asm volatile("s_waitcnt vmcnt(0)" ::: "memory");
  }
  BAR();

  int cur = 0, nxt = BUFE, stg = 2 * BUFE;
  for (int T = 0; T < nk; ++T) {
    // stage tile T+2 into the buffer freed by tile T-1 (readers retired
    // before the previous barrier)
    if (T + 2 < nk) {
      const int k2 = (T + 2) * BK;
      ST_A(stg, k2);
      ST_B(stg, k2);
    }

    // frag reads + MFMA; compiler schedules ds_reads/lgkmcnt/MFMA interleave
    short8 af[8], bq[4];
#pragma unroll
    for (int i = 0; i < 4; ++i)
      af[i] = *(const short8*)&lptr[cur + aoff + i * 512];
#pragma unroll
    for (int j = 0; j < 4; ++j)
      bq[j] = *(const short8*)&lptr[cur + boff + j * 512];

    __builtin_amdgcn_s_setprio(1);
#pragma unroll
    for (int i = 0; i < 4; ++i)
#pragma unroll
      for (int j = 0; j < 4; ++j)
        acc[i][j] = __builtin_amdgcn_mfma_f32_16x16x32_bf16(af[i], bq[j],
                                                            acc[i][j], 0, 0, 0);
    __builtin_amdgcn_s_setprio(0);

#pragma unroll
    for (int i = 4; i < 8; ++i)
      af[i] = *(const short8*)&lptr[cur + aoff + i * 512];

    __builtin_amdgcn_s_setprio(1);
#pragma unroll
    for (int i = 4; i < 8; ++i)
#pragma unroll
      for (int j = 0; j < 4; ++j)
        acc[i][j] = __builtin_amdgcn_mfma_f32_16x16x32_bf16(af[i], bq[j],
                                                            acc[i][j], 0, 0, 0);
    __builtin_amdgcn_s_setprio(0);

    // gate: tile T+1 must be fully staged; keep T+2's 4 loads in flight
    if (T + 1 < nk) {
      if (T + 2 < nk) {
        asm volatile("s_waitcnt vmcnt(4)" ::: "memory");
      } else {
        asm volatile("s_waitcnt vmcnt(0)" ::: "memory");
      }
    }
    BAR();  // nxt visible to all waves; cur's readers all retired

    const int t = cur;
    cur = nxt;
    nxt = stg;
    stg = t;
  }

  // epilogue: C/D layout col = lane&15, row = (lane>>4)*4 + q
  const float s = scales[sidx * 2];
  const int crow0 = rowA0 + wr * 128 + (lane >> 4) * 4;
  const int ccol0 = rowB0 + wc * 64 + (lane & 15);
  if (EPI == 0) {
    const float s2 = s * s;
    unsigned short* C = (unsigned short*)Cout;
#pragma unroll
    for (int ri = 0; ri < 8; ++ri)
#pragma unroll
      for (int ci = 0; ci < 4; ++ci)
#pragma unroll
        for (int q = 0; q < 4; ++q) {
          float v = acc[ri][ci][q];
          v = fmaxf(v, 0.0f);
          v = v * v * s2;
          C[(size_t)(crow0 + ri * 16 + q) * N + (ccol0 + ci * 16)] = f2bf(v);
        }
  } else {
    float* C = (float*)Cout;
#pragma unroll
    for (int ri = 0; ri < 8; ++ri)
#pragma unroll
      for (int ci = 0; ci < 4; ++ci)
#pragma unroll
        for (int q = 0; q < 4; ++q)
          C[(size_t)(crow0 + ri * 16 + q) * N + (ccol0 + ci * 16)] =
              acc[ri][ci][q] * s;
  }
}

extern "C" void kernel_launch(void* const* d_in, const int* in_sizes, int n_in,
                              void* d_out, int out_size, void* d_ws, size_t ws_size,
                              hipStream_t stream) {
  const int Mdim = 32768;  // B*S
  const int Ddim = 2048;
  const int Hdim = 5120;
  const int NW = Hdim * Ddim;  // elements per weight

  const float* x = (const float*)d_in[0];
  const float* w_fc = (const float*)d_in[1];
  const float* w_proj = (const float*)d_in[2];
  float* out = (float*)d_out;

  char* ws = (char*)d_ws;
  double* partial = (double*)ws;                          // 16 KB
  float* scales = (float*)(ws + 16384);                   // 4 floats
  unsigned short* wq_fc = (unsigned short*)(ws + 32768);  // 20 MB
  unsigned short* wq_proj = wq_fc + (size_t)NW;           // 20 MB
  unsigned short* xbf = wq_proj + (size_t)NW;             // 128 MB
  unsigned short* hbf = xbf + (size_t)Mdim * Ddim;        // 320 MB

  // 1) abs-mean reductions (deterministic, fp64)
  k_reduce_abs<<<1024, 256, 0, stream>>>((const float4*)w_fc, NW / 4, partial);
  k_reduce_abs<<<1024, 256, 0, stream>>>((const float4*)w_proj, NW / 4,
                                         partial + 1024);
  k_finalize<<<1, 256, 0, stream>>>(partial, scales, 1.0 / (double)NW);

  // 2) ternarize weights -> bf16 q
  k_ternarize<<<2048, 256, 0, stream>>>((const float4*)w_fc, (ushort4*)wq_fc,
                                        scales, 0, NW / 4);
  k_ternarize<<<2048, 256, 0, stream>>>((const float4*)w_proj, (ushort4*)wq_proj,
                                        scales, 1, NW / 4);

  // 3) x -> bf16
  k_f32_to_bf16<<<2048, 256, 0, stream>>>((const float4*)x, (ushort4*)xbf,
                                          (Mdim * Ddim) / 4);

  // 4) h = relu(x @ Wfc^T * s)^2  [M x H] bf16
  k_gemm_bt<0><<<dim3((Hdim / BN) * (Mdim / BM)), 512, 0, stream>>>(
      xbf, wq_fc, hbf, Mdim, Hdim, Ddim, scales, 0, Hdim / BN);

  // 5) out = h @ Wproj^T * s  [M x D] fp32
  k_gemm_bt<1><<<dim3((Ddim / BN) * (Mdim / BM)), 512, 0, stream>>>(
      hbf, wq_proj, out, Mdim, Ddim, Hdim, scales, 1, Ddim / BN);
}